// Round 1
// baseline (395.157 us; speedup 1.0000x reference)
//
#include <hip/hip_runtime.h>

// Problem constants (match reference setup_inputs)
#define N_NODES 500000
#define MEM_D   128
#define MSG_W   257          // MSG_D + 1
#define BATCH   200000

// d_out layout (floats, concatenated in return order):
//   [0)              mem_out      B * 128      = 25,600,000
//   [25,600,000)     lu_out       B            =    200,000
//   [25,800,000)     new_memory   N * 128      = 64,000,000
//   [89,800,000)     new_messages N * 257      = 128,500,000
// total = 218,300,000 floats

// ---------------------------------------------------------------------------
// Pass 1: build per-node "winner" (last batch position writing that node, for
// last-wins scatter semantics matching numpy) and a touched-flag for messages.
__global__ void scatter_idx_kernel(const int* __restrict__ node_idxs,
                                   const int* __restrict__ nodes,
                                   int* __restrict__ winner,
                                   unsigned char* __restrict__ flag) {
    int i = blockIdx.x * blockDim.x + threadIdx.x;
    int stride = gridDim.x * blockDim.x;
    for (; i < BATCH; i += stride) {
        atomicMax(&winner[node_idxs[i]], i);   // last occurrence wins
        flag[nodes[i]] = 1;                    // idempotent (same value), race OK
    }
}

// ---------------------------------------------------------------------------
// Pass 2a: mem_out = memory[node_idxs]  (row gather, float4)
//          lu_out  = last_update[node_idxs]
__global__ void gather_kernel(const float* __restrict__ memory,
                              const float* __restrict__ last_update,
                              const int* __restrict__ node_idxs,
                              float* __restrict__ mem_out,
                              float* __restrict__ lu_out) {
    const long total = (long)BATCH * (MEM_D / 4);   // 6.4M float4
    long i = (long)blockIdx.x * blockDim.x + threadIdx.x;
    long stride = (long)gridDim.x * blockDim.x;
    const float4* mem4 = reinterpret_cast<const float4*>(memory);
    float4* out4 = reinterpret_cast<float4*>(mem_out);
    for (; i < total; i += stride) {
        int row  = (int)(i >> 5);       // /32 float4 per row
        int col4 = (int)(i & 31);
        int idx  = node_idxs[row];
        out4[i] = mem4[(long)idx * 32 + col4];
        if (col4 == 0) lu_out[row] = last_update[idx];
    }
}

// ---------------------------------------------------------------------------
// Pass 2b: new_memory[n] = winner[n] >= 0 ? values[winner[n]] : memory[n]
// (fused full copy + last-wins row scatter, conflict-free)
__global__ void setmem_kernel(const float* __restrict__ memory,
                              const float* __restrict__ values,
                              const int* __restrict__ winner,
                              float* __restrict__ new_memory) {
    const long total = (long)N_NODES * (MEM_D / 4);   // 16M float4
    long i = (long)blockIdx.x * blockDim.x + threadIdx.x;
    long stride = (long)gridDim.x * blockDim.x;
    const float4* mem4 = reinterpret_cast<const float4*>(memory);
    const float4* val4 = reinterpret_cast<const float4*>(values);
    float4* out4 = reinterpret_cast<float4*>(new_memory);
    for (; i < total; i += stride) {
        int row  = (int)(i >> 5);
        int col4 = (int)(i & 31);
        int w = winner[row];            // broadcast across 32 consecutive lanes
        out4[i] = (w >= 0) ? val4[(long)w * 32 + col4] : mem4[i];
    }
}

// ---------------------------------------------------------------------------
// Pass 2c: new_messages[n] = flag[n] ? node_id_to_messages[n] : messages[n]
// Rows are 257 floats -> flat float4 with scalar fallback at row boundaries.
__global__ void setmsg_kernel(const float* __restrict__ messages,
                              const float* __restrict__ src,
                              const unsigned char* __restrict__ flag,
                              float* __restrict__ out) {
    const int total4 = (N_NODES / 4) * MSG_W;   // 128,500,000 / 4 = 32,125,000
    int i = blockIdx.x * blockDim.x + threadIdx.x;
    int stride = gridDim.x * blockDim.x;
    const float4* m4 = reinterpret_cast<const float4*>(messages);
    const float4* s4 = reinterpret_cast<const float4*>(src);
    float4* o4 = reinterpret_cast<float4*>(out);
    for (; i < total4; i += stride) {
        int e  = i * 4;
        int r0 = e / 257;
        int r3 = (e + 3) / 257;
        if (r0 == r3) {
            o4[i] = flag[r0] ? s4[i] : m4[i];
        } else {
            #pragma unroll
            for (int k = 0; k < 4; ++k) {
                int r = (e + k) / 257;
                out[e + k] = (flag[r] ? src : messages)[e + k];
            }
        }
    }
}

// ---------------------------------------------------------------------------
extern "C" void kernel_launch(void* const* d_in, const int* in_sizes, int n_in,
                              void* d_out, int out_size, void* d_ws, size_t ws_size,
                              hipStream_t stream) {
    const float* memory       = (const float*)d_in[0];   // [N, 128]
    const float* last_update  = (const float*)d_in[1];   // [N]
    const float* messages     = (const float*)d_in[2];   // [N, 257]
    const float* nid2msg      = (const float*)d_in[3];   // [N, 257]
    const float* values       = (const float*)d_in[4];   // [B, 128]
    const int*   node_idxs    = (const int*)d_in[5];     // [B]
    const int*   nodes        = (const int*)d_in[6];     // [B]

    float* out = (float*)d_out;
    float* mem_out      = out;
    float* lu_out       = out + (long)BATCH * MEM_D;                 // 25,600,000
    float* new_memory   = lu_out + BATCH;                            // 25,800,000
    float* new_messages = new_memory + (long)N_NODES * MEM_D;        // 89,800,000

    // Workspace: winner map (int[N]) + touched flag (uchar[N]) = 2.5 MB
    int* winner = (int*)d_ws;
    unsigned char* flag = (unsigned char*)d_ws + (size_t)N_NODES * sizeof(int);

    hipMemsetAsync(winner, 0xFF, (size_t)N_NODES * sizeof(int), stream);  // -1
    hipMemsetAsync(flag, 0, (size_t)N_NODES, stream);

    const int BS = 256;

    // Pass 1: index maps
    scatter_idx_kernel<<<(BATCH + BS - 1) / BS, BS, 0, stream>>>(
        node_idxs, nodes, winner, flag);

    // Pass 2: three independent bulk-move kernels (capped grid + grid-stride)
    gather_kernel<<<2048, BS, 0, stream>>>(memory, last_update, node_idxs,
                                           mem_out, lu_out);
    setmem_kernel<<<2048, BS, 0, stream>>>(memory, values, winner, new_memory);
    setmsg_kernel<<<2048, BS, 0, stream>>>(messages, nid2msg, flag, new_messages);
}

// Round 2
// 388.846 us; speedup vs baseline: 1.0162x; 1.0162x over previous
//
#include <hip/hip_runtime.h>

// Problem constants (match reference setup_inputs)
#define N_NODES 500000
#define MEM_D   128
#define MSG_W   257          // MSG_D + 1
#define BATCH   200000

// d_out layout (floats, concatenated in return order):
//   [0)              mem_out      B * 128      = 25,600,000
//   [25,600,000)     lu_out       B            =    200,000
//   [25,800,000)     new_memory   N * 128      = 64,000,000
//   [89,800,000)     new_messages N * 257      = 128,500,000

// ---------------------------------------------------------------------------
// Pass 1: per-node "winner" (last batch position writing that node -> numpy
// last-wins scatter semantics) and a touched-flag for messages.
__global__ void scatter_idx_kernel(const int* __restrict__ node_idxs,
                                   const int* __restrict__ nodes,
                                   int* __restrict__ winner,
                                   unsigned char* __restrict__ flag) {
    int i = blockIdx.x * blockDim.x + threadIdx.x;
    int stride = gridDim.x * blockDim.x;
    for (; i < BATCH; i += stride) {
        atomicMax(&winner[node_idxs[i]], i);   // last occurrence wins
        flag[nodes[i]] = 1;                    // idempotent (same value), race OK
    }
}

// ---------------------------------------------------------------------------
// Pass 2a: mem_out = memory[node_idxs] (row gather, float4); lu_out scalar gather.
__global__ void gather_kernel(const float* __restrict__ memory,
                              const float* __restrict__ last_update,
                              const int* __restrict__ node_idxs,
                              float* __restrict__ mem_out,
                              float* __restrict__ lu_out) {
    const long total = (long)BATCH * (MEM_D / 4);   // 6.4M float4
    long i = (long)blockIdx.x * blockDim.x + threadIdx.x;
    long stride = (long)gridDim.x * blockDim.x;
    const float4* mem4 = reinterpret_cast<const float4*>(memory);
    float4* out4 = reinterpret_cast<float4*>(mem_out);
    for (; i < total; i += stride) {
        int row  = (int)(i >> 5);       // 32 float4 per row
        int col4 = (int)(i & 31);
        int idx  = node_idxs[row];
        out4[i] = mem4[(long)idx * 32 + col4];
        if (col4 == 0) lu_out[row] = last_update[idx];
    }
}

// ---------------------------------------------------------------------------
// Pass 2b: new_memory[n] = winner[n] >= 0 ? values[winner[n]] : memory[n]
// Explicit if/else so only the selected source row is fetched.
__global__ void setmem_kernel(const float* __restrict__ memory,
                              const float* __restrict__ values,
                              const int* __restrict__ winner,
                              float* __restrict__ new_memory) {
    const long total = (long)N_NODES * (MEM_D / 4);   // 16M float4
    long i = (long)blockIdx.x * blockDim.x + threadIdx.x;
    long stride = (long)gridDim.x * blockDim.x;
    const float4* mem4 = reinterpret_cast<const float4*>(memory);
    const float4* val4 = reinterpret_cast<const float4*>(values);
    float4* out4 = reinterpret_cast<float4*>(new_memory);
    for (; i < total; i += stride) {
        int row  = (int)(i >> 5);
        int col4 = (int)(i & 31);
        int w = winner[row];            // uniform across the row's 32 lanes
        float4 v;
        if (w >= 0) {
            v = val4[(long)w * 32 + col4];
        } else {
            v = mem4[i];
        }
        out4[i] = v;
    }
}

// ---------------------------------------------------------------------------
// Pass 2c: new_messages[n] = flag[n] ? node_id_to_messages[n] : messages[n]
// Flat float4 with scalar fallback at row boundaries; explicit if/else so the
// unselected source row is never fetched (rows = 1028B >> 128B line).
__global__ void setmsg_kernel(const float* __restrict__ messages,
                              const float* __restrict__ src,
                              const unsigned char* __restrict__ flag,
                              float* __restrict__ out) {
    const int total4 = (N_NODES / 4) * MSG_W;   // 32,125,000 float4
    int i = blockIdx.x * blockDim.x + threadIdx.x;
    int stride = gridDim.x * blockDim.x;
    const float4* m4 = reinterpret_cast<const float4*>(messages);
    const float4* s4 = reinterpret_cast<const float4*>(src);
    float4* o4 = reinterpret_cast<float4*>(out);
    for (; i < total4; i += stride) {
        int e  = i * 4;
        int r0 = e / 257;
        int r3 = (e + 3) / 257;
        if (r0 == r3) {
            float4 v;
            if (flag[r0]) {
                v = s4[i];
            } else {
                v = m4[i];
            }
            o4[i] = v;
        } else {
            #pragma unroll
            for (int k = 0; k < 4; ++k) {
                int r = (e + k) / 257;
                float v;
                if (flag[r]) {
                    v = src[e + k];
                } else {
                    v = messages[e + k];
                }
                out[e + k] = v;
            }
        }
    }
}

// ---------------------------------------------------------------------------
extern "C" void kernel_launch(void* const* d_in, const int* in_sizes, int n_in,
                              void* d_out, int out_size, void* d_ws, size_t ws_size,
                              hipStream_t stream) {
    const float* memory       = (const float*)d_in[0];   // [N, 128]
    const float* last_update  = (const float*)d_in[1];   // [N]
    const float* messages     = (const float*)d_in[2];   // [N, 257]
    const float* nid2msg      = (const float*)d_in[3];   // [N, 257]
    const float* values       = (const float*)d_in[4];   // [B, 128]
    const int*   node_idxs    = (const int*)d_in[5];     // [B]
    const int*   nodes        = (const int*)d_in[6];     // [B]

    float* out = (float*)d_out;
    float* mem_out      = out;
    float* lu_out       = out + (long)BATCH * MEM_D;                 // 25,600,000
    float* new_memory   = lu_out + BATCH;                            // 25,800,000
    float* new_messages = new_memory + (long)N_NODES * MEM_D;        // 89,800,000

    // Workspace: winner map (int[N]) + touched flag (uchar[N]) = 2.5 MB
    int* winner = (int*)d_ws;
    unsigned char* flag = (unsigned char*)d_ws + (size_t)N_NODES * sizeof(int);

    hipMemsetAsync(winner, 0xFF, (size_t)N_NODES * sizeof(int), stream);  // -1
    hipMemsetAsync(flag, 0, (size_t)N_NODES, stream);

    const int BS = 256;

    // Pass 1: index maps
    scatter_idx_kernel<<<(BATCH + BS - 1) / BS, BS, 0, stream>>>(
        node_idxs, nodes, winner, flag);

    // Pass 2: three independent bulk-move kernels (capped grid + grid-stride)
    gather_kernel<<<2048, BS, 0, stream>>>(memory, last_update, node_idxs,
                                           mem_out, lu_out);
    setmem_kernel<<<2048, BS, 0, stream>>>(memory, values, winner, new_memory);
    setmsg_kernel<<<2048, BS, 0, stream>>>(messages, nid2msg, flag, new_messages);
}

// Round 3
// 360.688 us; speedup vs baseline: 1.0956x; 1.0781x over previous
//
#include <hip/hip_runtime.h>

// Problem constants (match reference setup_inputs)
#define N_NODES 500000
#define MEM_D   128
#define MSG_W   257          // MSG_D + 1
#define BATCH   200000

// Fused work-index space (units = float4 slots, except gather col0 also does lu)
#define G_UNITS   6400000    // BATCH * 32       (gather mem_out)
#define M_UNITS   16000000   // N_NODES * 32     (new_memory)
#define S_UNITS   32125000   // (N_NODES/4)*257  (new_messages)
#define GM_UNITS  22400000   // G_UNITS + M_UNITS
#define TOTAL_UNITS 54525000 // G + M + S

typedef float f4 __attribute__((ext_vector_type(4)));

__device__ __forceinline__ f4 nt_load4(const f4* p) {
    return __builtin_nontemporal_load(p);
}
__device__ __forceinline__ void nt_store4(f4* p, f4 v) {
    __builtin_nontemporal_store(v, p);
}

// ---------------------------------------------------------------------------
// Init: winner = -1 (int[N]), flag = 0 (uchar[N], written as u32)
__global__ void init_kernel(int* __restrict__ winner,
                            unsigned int* __restrict__ flag32) {
    int i = blockIdx.x * blockDim.x + threadIdx.x;
    int stride = gridDim.x * blockDim.x;
    for (int j = i; j < N_NODES; j += stride) winner[j] = -1;
    for (int j = i; j < N_NODES / 4; j += stride) flag32[j] = 0u;  // 125,000 exact
}

// ---------------------------------------------------------------------------
// Pass 1: last-wins winner map + touched flag
__global__ void scatter_idx_kernel(const int* __restrict__ node_idxs,
                                   const int* __restrict__ nodes,
                                   int* __restrict__ winner,
                                   unsigned char* __restrict__ flag) {
    int i = blockIdx.x * blockDim.x + threadIdx.x;
    int stride = gridDim.x * blockDim.x;
    for (; i < BATCH; i += stride) {
        atomicMax(&winner[node_idxs[i]], i);   // last occurrence wins
        flag[nodes[i]] = 1;                    // idempotent, race OK
    }
}

// ---------------------------------------------------------------------------
// Pass 2 (fused): three bulk-move jobs in one grid-stride index space.
//   [0, G_UNITS)        : mem_out = memory[node_idxs] (+ lu_out at col0)
//   [G_UNITS, GM_UNITS) : new_memory = winner>=0 ? values[winner] : memory
//   [GM_UNITS, TOTAL)   : new_messages = flag ? nid2msg : messages
__global__ void fused_kernel(const float* __restrict__ memory,
                             const float* __restrict__ last_update,
                             const float* __restrict__ messages,
                             const float* __restrict__ nid2msg,
                             const float* __restrict__ values,
                             const int* __restrict__ node_idxs,
                             const int* __restrict__ winner,
                             const unsigned char* __restrict__ flag,
                             float* __restrict__ mem_out,
                             float* __restrict__ lu_out,
                             float* __restrict__ new_memory,
                             float* __restrict__ new_messages) {
    const f4* mem4 = reinterpret_cast<const f4*>(memory);
    const f4* val4 = reinterpret_cast<const f4*>(values);
    const f4* msg4 = reinterpret_cast<const f4*>(messages);
    const f4* src4 = reinterpret_cast<const f4*>(nid2msg);
    f4* memout4 = reinterpret_cast<f4*>(mem_out);
    f4* newmem4 = reinterpret_cast<f4*>(new_memory);
    f4* newmsg4 = reinterpret_cast<f4*>(new_messages);

    int i = blockIdx.x * blockDim.x + threadIdx.x;
    int stride = gridDim.x * blockDim.x;
    for (; i < TOTAL_UNITS; i += stride) {
        if (i < G_UNITS) {
            // ---- gather: 32 float4 per batch row, scattered source rows ----
            int row  = i >> 5;
            int col4 = i & 31;
            int idx  = node_idxs[row];
            f4 v = mem4[(long)idx * 32 + col4];      // cached: duplicate rows
            nt_store4(&memout4[i], v);
            if (col4 == 0) {
                __builtin_nontemporal_store(last_update[idx], &lu_out[row]);
            }
        } else if (i < GM_UNITS) {
            // ---- set_memory: copy-or-replace, conflict-free ----
            int j    = i - G_UNITS;
            int row  = j >> 5;
            int col4 = j & 31;
            int w = winner[row];                     // uniform across row
            f4 v;
            if (w >= 0) {
                v = val4[(long)w * 32 + col4];       // cached: scattered gather
            } else {
                v = nt_load4(&mem4[j]);              // pure stream
            }
            nt_store4(&newmem4[j], v);
        } else {
            // ---- messages: flag-select row copy, rows of 257 floats ----
            int j = i - GM_UNITS;
            int e  = j * 4;
            int r0 = e / 257;
            int r3 = (e + 3) / 257;
            if (r0 == r3) {
                f4 v;
                if (flag[r0]) {
                    v = nt_load4(&src4[j]);
                } else {
                    v = nt_load4(&msg4[j]);
                }
                nt_store4(&newmsg4[j], v);
            } else {
                #pragma unroll
                for (int k = 0; k < 4; ++k) {
                    int r = (e + k) / 257;
                    float v = (flag[r] ? nid2msg : messages)[e + k];
                    new_messages[e + k] = v;
                }
            }
        }
    }
}

// ---------------------------------------------------------------------------
extern "C" void kernel_launch(void* const* d_in, const int* in_sizes, int n_in,
                              void* d_out, int out_size, void* d_ws, size_t ws_size,
                              hipStream_t stream) {
    const float* memory       = (const float*)d_in[0];   // [N, 128]
    const float* last_update  = (const float*)d_in[1];   // [N]
    const float* messages     = (const float*)d_in[2];   // [N, 257]
    const float* nid2msg      = (const float*)d_in[3];   // [N, 257]
    const float* values       = (const float*)d_in[4];   // [B, 128]
    const int*   node_idxs    = (const int*)d_in[5];     // [B]
    const int*   nodes        = (const int*)d_in[6];     // [B]

    float* out = (float*)d_out;
    float* mem_out      = out;
    float* lu_out       = out + (long)BATCH * MEM_D;                 // 25,600,000
    float* new_memory   = lu_out + BATCH;                            // 25,800,000
    float* new_messages = new_memory + (long)N_NODES * MEM_D;        // 89,800,000

    // Workspace: winner map (int[N]) + touched flag (uchar[N]) = 2.5 MB
    int* winner = (int*)d_ws;
    unsigned char* flag = (unsigned char*)d_ws + (size_t)N_NODES * sizeof(int);

    const int BS = 256;

    // 1. init maps (replaces two memsets -> one tiny kernel)
    init_kernel<<<512, BS, 0, stream>>>(winner, (unsigned int*)flag);

    // 2. index maps
    scatter_idx_kernel<<<(BATCH + BS - 1) / BS, BS, 0, stream>>>(
        node_idxs, nodes, winner, flag);

    // 3. one fused bulk-move kernel (grid-stride over 54.5M float4 units)
    fused_kernel<<<2048, BS, 0, stream>>>(memory, last_update, messages,
                                          nid2msg, values, node_idxs,
                                          winner, flag,
                                          mem_out, lu_out, new_memory,
                                          new_messages);
}